// Round 6
// baseline (119.978 us; speedup 1.0000x reference)
//
#include <hip/hip_runtime.h>

// Depth-4 path signature of [64,512,10] fp32 via time-split Chen scan.
// R6: prefix-lane sig kernel with ALL accumulator state as macro-generated
// NAMED SCALARS (no arrays anywhere in the hot loop) -> guaranteed VGPR
// residency, no SROA/scratch risk. One lane owns (i,j): a1, a2, a3_k x10,
// a4_k_l x100. Per step: ~127 straight-line FMAs + 5 prefetched LDS reads.
//  K1 sig_group_kernel: 64 b x 8 g blocks (128 thr), 64 steps each.
//  K2 combine_kernel:   64 b x 5 k-part blocks fold 8 group sigs (Chen).

#define CH     10
#define LEN    512
#define NB     64
#define GROUPS 8
#define SPG    64              // steps/group (tail padded with dx=0)
#define SIGSZ  11110           // output: 10 + 100 + 1000 + 10000
#define SIGW   11112           // ws sig stride; level4 at 1112
#define L4W    1112
#define TSTR   68              // transposed LDS stride (floats)

#define FORALL10(M) M(0) M(1) M(2) M(3) M(4) M(5) M(6) M(7) M(8) M(9)

__global__ __launch_bounds__(128, 2)
void sig_group_kernel(const float* __restrict__ path, float* __restrict__ wsig) {
    __shared__ __align__(16) float rowL[(SPG + 1) * 12];  // +1 pad step (zeros)
    __shared__ __align__(16) float dxT[CH * TSTR];        // transposed dx
    const int tid = threadIdx.x;
    const int b   = blockIdx.x >> 3;
    const int g   = blockIdx.x & 7;
    const int s0  = g * SPG;

    const float* __restrict__ pb = path + b * (LEN * CH);
    for (int e = tid; e < (SPG + 1) * CH; e += 128) {
        int s = e / CH, c = e - s * CH;
        int gs = s0 + s;
        float v = 0.f;
        if (s < SPG && gs < LEN - 1)
            v = pb[gs * CH + c + CH] - pb[gs * CH + c];
        rowL[s * 12 + c] = v;
        dxT[c * TSTR + s] = v;
    }
    __syncthreads();

    const int ij = (tid < 100) ? tid : tid - 28;   // dup lanes: benign
    const int i = ij / 10, j = ij % 10;

    float a1 = 0.f, a2 = 0.f;
#define DECL_ACC(K) float a3_##K = 0.f, a4_##K##_0 = 0.f, a4_##K##_1 = 0.f, \
    a4_##K##_2 = 0.f, a4_##K##_3 = 0.f, a4_##K##_4 = 0.f, a4_##K##_5 = 0.f, \
    a4_##K##_6 = 0.f, a4_##K##_7 = 0.f, a4_##K##_8 = 0.f, a4_##K##_9 = 0.f;
    FORALL10(DECL_ACC)

    // pipeline preload: step 0
    float4 cA = *(const float4*)(rowL);
    float4 cB = *(const float4*)(rowL + 4);
    float2 cC = *(const float2*)(rowL + 8);
    float dxi = dxT[i * TSTR];
    float dxj = dxT[j * TSTR];

    for (int s = 0; s < SPG; ++s) {
        // prefetch step s+1 (row SPG is zeros; never OOB)
        const float* nrow = rowL + (s + 1) * 12;
        const float4 nA = *(const float4*)(nrow);
        const float4 nB = *(const float4*)(nrow + 4);
        const float2 nC = *(const float2*)(nrow + 8);
        const float ndxi = dxT[i * TSTR + s + 1];
        const float ndxj = dxT[j * TSTR + s + 1];

        const float r0 = cA.x, r1 = cA.y, r2 = cA.z, r3 = cA.w;
        const float r4 = cB.x, r5 = cB.y, r6 = cB.z, r7 = cB.w;
        const float r8 = cC.x, r9 = cC.y;

        const float p1 = fmaf(dxi, 1.f / 24.f, a1 * (1.f / 6.f));
        const float q1 = fmaf(dxi, 1.f / 6.f,  a1 * 0.5f);
        const float rr = fmaf(dxi, 0.5f, a1);
        const float p2 = fmaf(p1, dxj, a2 * 0.5f);
        const float q2 = fmaf(q1, dxj, a2);
        a2 = fmaf(rr, dxj, a2);
        a1 += dxi;

#define STEP_K(K) { const float p3 = fmaf(p2, r##K, a3_##K); \
        a3_##K = fmaf(q2, r##K, a3_##K); \
        a4_##K##_0 = fmaf(p3, r0, a4_##K##_0); \
        a4_##K##_1 = fmaf(p3, r1, a4_##K##_1); \
        a4_##K##_2 = fmaf(p3, r2, a4_##K##_2); \
        a4_##K##_3 = fmaf(p3, r3, a4_##K##_3); \
        a4_##K##_4 = fmaf(p3, r4, a4_##K##_4); \
        a4_##K##_5 = fmaf(p3, r5, a4_##K##_5); \
        a4_##K##_6 = fmaf(p3, r6, a4_##K##_6); \
        a4_##K##_7 = fmaf(p3, r7, a4_##K##_7); \
        a4_##K##_8 = fmaf(p3, r8, a4_##K##_8); \
        a4_##K##_9 = fmaf(p3, r9, a4_##K##_9); }
        FORALL10(STEP_K)

        cA = nA; cB = nB; cC = nC; dxi = ndxi; dxj = ndxj;
    }

    float* wb = wsig + (b * GROUPS + g) * SIGW;
#define STORE_K(K) { wb[110 + ij * 10 + K] = a3_##K; \
        float* o = wb + L4W + ij * 100 + K * 10; \
        *(float2*)(o)     = make_float2(a4_##K##_0, a4_##K##_1); \
        *(float2*)(o + 2) = make_float2(a4_##K##_2, a4_##K##_3); \
        *(float2*)(o + 4) = make_float2(a4_##K##_4, a4_##K##_5); \
        *(float2*)(o + 6) = make_float2(a4_##K##_6, a4_##K##_7); \
        *(float2*)(o + 8) = make_float2(a4_##K##_8, a4_##K##_9); }
    FORALL10(STORE_K)
    wb[10 + ij] = a2;
    if (j == 0) wb[i] = a1;
}

__global__ __launch_bounds__(128, 1)
void combine_kernel(const float* __restrict__ wsig, float* __restrict__ out) {
    __shared__ float Bs[1110];                  // B1|B2|B3 of right factor
    const int tid  = threadIdx.x;
    const int b    = blockIdx.x / 5;
    const int part = blockIdx.x % 5;            // level-4 k-pair: k0 = 2*part
    const int k0   = part * 2;
    const int ij = (tid < 100) ? tid : tid - 28;
    const int i = ij / 10, j = ij % 10;

    const float* __restrict__ w0 = wsig + b * GROUPS * SIGW;
    float a1 = w0[i];
    float a2 = w0[10 + ij];
    float a3[10], a4[20];
    #pragma unroll
    for (int k = 0; k < 10; ++k) a3[k] = w0[110 + ij * 10 + k];
    {
        const float2* p2 = (const float2*)(w0 + L4W + ij * 100 + k0 * 10);
        #pragma unroll
        for (int m = 0; m < 10; ++m) {
            float2 v = p2[m];
            a4[2 * m] = v.x; a4[2 * m + 1] = v.y;
        }
    }

    for (int g = 1; g < GROUPS; ++g) {
        const float* __restrict__ wg = w0 + g * SIGW;
        __syncthreads();                        // protect Bs reuse
        for (int e = tid; e < 1110; e += 128) Bs[e] = wg[e];
        __syncthreads();
        float b4[20];
        const float2* b2p = (const float2*)(wg + L4W + ij * 100 + k0 * 10);
        #pragma unroll
        for (int m = 0; m < 10; ++m) {
            float2 v = b2p[m];
            b4[2 * m] = v.x; b4[2 * m + 1] = v.y;
        }
        #pragma unroll
        for (int kk = 0; kk < 2; ++kk) {
            const int k = k0 + kk;
            #pragma unroll
            for (int l = 0; l < 10; ++l)
                a4[kk * 10 + l] += a3[k] * Bs[l] + a2 * Bs[10 + k * 10 + l]
                                 + a1 * Bs[110 + (j * 10 + k) * 10 + l]
                                 + b4[kk * 10 + l];
        }
        #pragma unroll
        for (int k = 0; k < 10; ++k)
            a3[k] += a2 * Bs[k] + a1 * Bs[10 + j * 10 + k] + Bs[110 + ij * 10 + k];
        a2 += a1 * Bs[j] + Bs[10 + ij];
        a1 += Bs[i];
    }

    float* ob = out + b * SIGSZ;
    float2* o2 = (float2*)(ob + 1110 + ij * 100 + k0 * 10);
    #pragma unroll
    for (int m = 0; m < 10; ++m)
        o2[m] = make_float2(a4[2 * m], a4[2 * m + 1]);
    if (part == 0) {
        #pragma unroll
        for (int k = 0; k < 10; ++k) ob[110 + ij * 10 + k] = a3[k];
        ob[10 + ij] = a2;
        if (j == 0) ob[i] = a1;
    }
}

extern "C" void kernel_launch(void* const* d_in, const int* in_sizes, int n_in,
                              void* d_out, int out_size, void* d_ws, size_t ws_size,
                              hipStream_t stream) {
    const float* path = (const float*)d_in[0];   // [64,512,10] fp32
    float* out  = (float*)d_out;                 // [64,11110] fp32
    float* wsig = (float*)d_ws;                  // [64][8][11112] (~22.8 MB)

    sig_group_kernel<<<dim3(NB * GROUPS), dim3(128), 0, stream>>>(path, wsig);
    combine_kernel<<<dim3(NB * 5), dim3(128), 0, stream>>>(wsig, out);
}